// Round 7
// baseline (562.181 us; speedup 1.0000x reference)
//
#include <hip/hip_runtime.h>
#include <math.h>

constexpr int T = 4096;
constexpr int C = 1024;
constexpr int D = 256;
constexpr int VOCAB = 32000;
constexpr int VQ = VOCAB / 4;              // 8000 floats = 31.25 KB LDS
constexpr int NT2 = T / 128;               // 32 tiles of 128
constexpr int NTILES2 = NT2 * (NT2 + 1) / 2;  // 528 causal 128-tiles

typedef __attribute__((ext_vector_type(8))) short bf16x8;
typedef __attribute__((ext_vector_type(4))) float f32x4;

__device__ inline unsigned short f2bf(float f) {
    union { float f; unsigned int u; } v; v.f = f;
    unsigned int u = v.u + 0x7FFFu + ((v.u >> 16) & 1u);   // RTNE
    return (unsigned short)(u >> 16);
}
__device__ inline float bf2f(unsigned short s) {
    union { unsigned int u; float f; } v; v.u = ((unsigned int)s) << 16;
    return v.f;
}
// async global->LDS, 16B per lane; LDS dest = wave-uniform base + lane*16
__device__ inline void gl_lds16(const unsigned short* g, unsigned short* l) {
    __builtin_amdgcn_global_load_lds(
        (const __attribute__((address_space(1))) unsigned int*)g,
        (__attribute__((address_space(3))) unsigned int*)l, 16, 0, 0);
}

// ---------------------------------------------------------------------------
// Prep: blocks [0,2048): x fp32 -> bf16 (8 elems/thread)
//       blocks [2048,2176): W [C][D] fp32 -> WT [512][C] bf16 transposed
// ---------------------------------------------------------------------------
__global__ __launch_bounds__(256) void prep_kernel(
    const float* __restrict__ x,
    const float* __restrict__ Wq, const float* __restrict__ Wk,
    unsigned short* __restrict__ xb, unsigned short* __restrict__ WT)
{
    const int tid = threadIdx.x;
    if (blockIdx.x < 2048) {
        const int i = (blockIdx.x * 256 + tid) * 8;
        float4 a = *(const float4*)(x + i);
        float4 b = *(const float4*)(x + i + 4);
        union { bf16x8 v; unsigned short s[8]; } o;
        o.s[0] = f2bf(a.x); o.s[1] = f2bf(a.y); o.s[2] = f2bf(a.z); o.s[3] = f2bf(a.w);
        o.s[4] = f2bf(b.x); o.s[5] = f2bf(b.y); o.s[6] = f2bf(b.z); o.s[7] = f2bf(b.w);
        *(bf16x8*)(xb + i) = o.v;
    } else {
        const int bid = blockIdx.x - 2048;        // 128 blocks
        const int w  = bid >> 6;                  // 0=Wq, 1=Wk
        const int rem = bid & 63;
        const int k0 = (rem >> 2) * 64;           // 16 k-tiles
        const int n0 = (rem & 3) * 64;            // 4 n-tiles
        const float* W = w ? Wk : Wq;
        __shared__ float tile[64][65];
        #pragma unroll
        for (int p = 0; p < 16; ++p) {
            const int e = p * 256 + tid;
            const int r = e >> 6, c = e & 63;
            tile[c][r] = W[(size_t)(k0 + r) * D + n0 + c];
        }
        __syncthreads();
        #pragma unroll
        for (int p = 0; p < 2; ++p) {
            const int e = p * 256 + tid;
            const int rr = e >> 3, cc = e & 7;
            union { bf16x8 v; unsigned short s[8]; } o;
            #pragma unroll
            for (int i = 0; i < 8; ++i) o.s[i] = f2bf(tile[rr][cc * 8 + i]);
            *(bf16x8*)(WT + (size_t)(w * D + n0 + rr) * C + k0 + cc * 8) = o.v;
        }
    }
}

// ---------------------------------------------------------------------------
// Kernel 1: qk[T][512] bf16 = xb[T][C] @ WT[512][C]^T
// 64x64 tile, 4 waves 2x2, BK=64, raw K-major LDS + global_load_lds(16B).
// ---------------------------------------------------------------------------
__global__ __launch_bounds__(256) void qk_mfma_kernel(
    const unsigned short* __restrict__ xb,
    const unsigned short* __restrict__ WT,
    unsigned short* __restrict__ qk)
{
    const int m0 = blockIdx.x * 64, n0 = blockIdx.y * 64;
    __shared__ __align__(16) unsigned short As[64 * 64];
    __shared__ __align__(16) unsigned short Bs[64 * 64];
    const int tid = threadIdx.x;
    const int wave = tid >> 6, lane = tid & 63;
    const int quad = lane >> 4, lr = lane & 15;
    const int wm = wave >> 1, wn = wave & 1;
    const int rsub = lane >> 3, c8 = (lane & 7) * 8;   // staging lane map

    f32x4 acc[2][2] = {};

    for (int k0 = 0; k0 < C; k0 += 64) {
        #pragma unroll
        for (int q = 0; q < 2; ++q) {
            const int ch = wave * 2 + q;               // 0..7, 8 rows each
            const int r = ch * 8 + rsub;
            gl_lds16(xb + (size_t)(m0 + r) * C + k0 + c8, As + ch * 512);
            gl_lds16(WT + (size_t)(n0 + r) * C + k0 + c8, Bs + ch * 512);
        }
        __syncthreads();
        #pragma unroll
        for (int kk = 0; kk < 64; kk += 32) {
            bf16x8 a[2], b[2];
            #pragma unroll
            for (int s = 0; s < 2; ++s) {
                a[s] = *(const bf16x8*)(As + (wm * 32 + s * 16 + lr) * 64 + kk + quad * 8);
                b[s] = *(const bf16x8*)(Bs + (wn * 32 + s * 16 + lr) * 64 + kk + quad * 8);
            }
            #pragma unroll
            for (int i = 0; i < 2; ++i)
                #pragma unroll
                for (int j = 0; j < 2; ++j)
                    acc[i][j] = __builtin_amdgcn_mfma_f32_16x16x32_bf16(
                        a[i], b[j], acc[i][j], 0, 0, 0);
        }
        __syncthreads();
    }

    #pragma unroll
    for (int i = 0; i < 2; ++i)
        #pragma unroll
        for (int j = 0; j < 2; ++j)
            #pragma unroll
            for (int r = 0; r < 4; ++r) {
                const int row = m0 + wm * 32 + i * 16 + quad * 4 + r;
                const int col = n0 + wn * 32 + j * 16 + lr;
                qk[(size_t)row * 512 + col] = f2bf(acc[i][j][r]);
            }
}

// ---------------------------------------------------------------------------
// Kernel 2: causal 128x128 tiles of c = (q @ k^T)/256, masked, written as
// bf16 packed row-contiguous: row t at 4096*(ti64*(ti64+1)/2) + (t&63)*len,
// len = ((t>>6)+1)*64.  4 waves, each owns a 64x64 quadrant. BK=64.
// ---------------------------------------------------------------------------
__global__ __launch_bounds__(256) void qkt_mfma_kernel(
    const unsigned short* __restrict__ qk,
    unsigned short* __restrict__ cpack)
{
    const int bid = blockIdx.x;
    int TI = (int)((sqrtf(8.0f * (float)bid + 1.0f) - 1.0f) * 0.5f);
    while ((TI + 1) * (TI + 2) / 2 <= bid) ++TI;
    while (TI * (TI + 1) / 2 > bid) --TI;
    const int TJ = bid - TI * (TI + 1) / 2;

    // one 32 KB buffer: staging As(16K)+Bs(16K), reused as 128x128 bf16 C
    __shared__ __align__(16) unsigned short S[128 * 128];
    unsigned short* As = S;                 // [128][64]
    unsigned short* Bs = S + 128 * 64;      // [128][64]

    const int tid = threadIdx.x;
    const int wave = tid >> 6, lane = tid & 63;
    const int quad = lane >> 4, lr = lane & 15;
    const int wm = wave >> 1, wn = wave & 1;
    const int rsub = lane >> 3, c8 = (lane & 7) * 8;

    f32x4 acc[4][4] = {};

    const unsigned short* qp = qk + (size_t)TI * 128 * 512;        // q rows
    const unsigned short* kp = qk + (size_t)TJ * 128 * 512 + 256;  // k rows

    for (int k0 = 0; k0 < D; k0 += 64) {
        #pragma unroll
        for (int p = 0; p < 4; ++p) {
            const int rb = wave * 32 + p * 8;          // 8 rows per DMA
            const int r = rb + rsub;
            gl_lds16(qp + (size_t)r * 512 + k0 + c8, As + rb * 64);
            gl_lds16(kp + (size_t)r * 512 + k0 + c8, Bs + rb * 64);
        }
        __syncthreads();
        #pragma unroll
        for (int kk = 0; kk < 64; kk += 32) {
            bf16x8 a[4], b[4];
            #pragma unroll
            for (int s = 0; s < 4; ++s) {
                a[s] = *(const bf16x8*)(As + (wm * 64 + s * 16 + lr) * 64 + kk + quad * 8);
                b[s] = *(const bf16x8*)(Bs + (wn * 64 + s * 16 + lr) * 64 + kk + quad * 8);
            }
            #pragma unroll
            for (int i = 0; i < 4; ++i)
                #pragma unroll
                for (int j = 0; j < 4; ++j)
                    acc[i][j] = __builtin_amdgcn_mfma_f32_16x16x32_bf16(
                        a[i], b[j], acc[i][j], 0, 0, 0);
        }
        __syncthreads();
    }

    // epilogue: mask+scale -> bf16 128x128 tile in S, then packed write
    const float scale = 1.0f / 256.0f;
    #pragma unroll
    for (int i = 0; i < 4; ++i)
        #pragma unroll
        for (int j = 0; j < 4; ++j)
            #pragma unroll
            for (int r = 0; r < 4; ++r) {
                const int row = wm * 64 + i * 16 + quad * 4 + r;
                const int col = wn * 64 + j * 16 + lr;
                const int rg = TI * 128 + row, cg = TJ * 128 + col;
                S[row * 128 + col] = f2bf((cg <= rg) ? acc[i][j][r] * scale : 0.0f);
            }
    __syncthreads();

    #pragma unroll
    for (int p = 0; p < 8; ++p) {
        const int cidx = p * 256 + tid;       // 2048 chunks of 8 cols
        const int row = cidx >> 4, col8 = (cidx & 15) * 8;
        const int t = TI * 128 + row;
        const int ti64 = t >> 6, il = t & 63;
        const int len = (ti64 + 1) * 64;
        const int gcol = TJ * 128 + col8;
        if (gcol < len) {
            const size_t base = (size_t)4096 * ((size_t)ti64 * (ti64 + 1) / 2)
                              + (size_t)il * len;
            *(bf16x8*)(cpack + base + gcol) = *(const bf16x8*)(S + row * 128 + col8);
        }
    }
}

// ---------------------------------------------------------------------------
// Kernel 3: one block per (row t, vocab quarter). LDS histogram + dense
// nontemporal write. 31.25 KB LDS, 512 thr -> 4 blocks/CU = 32 waves/CU.
// ---------------------------------------------------------------------------
__global__ __launch_bounds__(512) void row_scatter_kernel(
    const unsigned short* __restrict__ cpack,
    const int* __restrict__ idx,
    float* __restrict__ out)
{
    __shared__ f32x4 hist4[VQ / 4];            // 31.25 KB
    float* hist = (float*)hist4;

    const int t  = blockIdx.x;
    const int lo = blockIdx.y * VQ;
    const int tid = threadIdx.x;

    const f32x4 z4 = {0.0f, 0.0f, 0.0f, 0.0f};
    for (int v = tid; v < VQ / 4; v += 512) hist4[v] = z4;
    __syncthreads();

    const int ti = t >> 6, il = t & 63;
    const int len = (ti + 1) * 64;
    const unsigned short* rowp =
        cpack + (size_t)4096 * ((size_t)ti * (ti + 1) / 2) + (size_t)il * len;
    const int nch = len >> 3;                  // 8..512 chunks of 8 elems

    for (int ch = tid; ch < nch; ch += 512) {
        union { bf16x8 v; unsigned short s[8]; } cv;
        cv.v = *(const bf16x8*)(rowp + ch * 8);
        union { int4 a[2]; int j[8]; } ji;
        ji.a[0] = *(const int4*)(idx + ch * 8);
        ji.a[1] = *(const int4*)(idx + ch * 8 + 4);
        #pragma unroll
        for (int i = 0; i < 8; ++i) {
            const int v = ji.j[i] - lo;
            if ((unsigned)v < (unsigned)VQ) {
                const float f = bf2f(cv.s[i]);
                if (f != 0.0f) atomicAdd(&hist[v], f);
            }
        }
    }
    __syncthreads();

    f32x4* orow = (f32x4*)(out + (size_t)t * VOCAB + lo);
    for (int v = tid; v < VQ / 4; v += 512)
        __builtin_nontemporal_store(hist4[v], orow + v);
}

// ---------------------------------------------------------------------------
extern "C" void kernel_launch(void* const* d_in, const int* in_sizes, int n_in,
                              void* d_out, int out_size, void* d_ws, size_t ws_size,
                              hipStream_t stream)
{
    const float* x   = (const float*)d_in[0];
    const int*   idx = (const int*)d_in[1];
    const float* Wq  = (const float*)d_in[2];
    const float* Wk  = (const float*)d_in[3];
    float* out = (float*)d_out;

    // ws: xb 8MB | WT 1MB | qk 4MB | cpack 17MB  => ~30MB
    unsigned short* xb = (unsigned short*)d_ws;
    unsigned short* WT = xb + (size_t)T * C;
    unsigned short* qk = WT + (size_t)2 * D * C;
    unsigned short* cpack = qk + (size_t)T * 2 * D;

    prep_kernel<<<dim3(2048 + 128), 256, 0, stream>>>(x, Wq, Wk, xb, WT);
    qk_mfma_kernel<<<dim3(T / 64, (2 * D) / 64), 256, 0, stream>>>(xb, WT, qk);
    qkt_mfma_kernel<<<dim3(NTILES2), 256, 0, stream>>>(qk, cpack);
    row_scatter_kernel<<<dim3(T, 4), 512, 0, stream>>>(cpack, idx, out);
}